// Round 1
// baseline (53389.453 us; speedup 1.0000x reference)
//
#include <hip/hip_runtime.h>
#include <math.h>

// Problem constants
#define B_   64
#define U_   1024
#define E_   512
#define D_   640
#define L4_  2560
#define TC   64          // time-chunk length
#define NCH  16          // number of chunks (TC*NCH == U_)

// ---------------------------------------------------------------------------
// GEMM: C[t][n][b] = bias[n] + sum_k A[m][k] * W[k][n],  m = t*64 + b
// MODE 0: A row m comes from embed[targets[b][t0+t]] (gather), K = 512
// MODE 1: A is h0c with layout [t][k][b] (stride 640*64 per t),  K = 640
// Block tile 128x128, 256 threads, 8x8 per-thread tile, BK=8.
// ---------------------------------------------------------------------------
template <int MODE>
__global__ __launch_bounds__(256) void gemm_kernel(
    const float* __restrict__ A,        // MODE0: embed [V][E]; MODE1: h0c [TC][640][64]
    const int*   __restrict__ targets,  // [B][U], used in MODE0
    const float* __restrict__ Wm,       // [K][2560]
    const float* __restrict__ bias,     // [2560]
    float* __restrict__ xz,             // [TC][2560][64]
    int K, int t0)
{
    const int tid = threadIdx.x;
    const int m0 = blockIdx.x * 128;
    const int n0 = blockIdx.y * 128;

    __shared__ float As[8][132];
    __shared__ float Bs[8][132];

    float acc[8][8];
#pragma unroll
    for (int i = 0; i < 8; ++i)
#pragma unroll
        for (int j = 0; j < 8; ++j) acc[i][j] = 0.f;

    // --- per-thread A loader setup ---
    const float* a_ptr;
    int a_ml = 0, a_kq = 0, a_k = 0;
    if (MODE == 0) {
        a_ml = tid & 127;               // row within tile
        a_kq = (tid >> 7) * 4;          // k offset (0 or 4)
        int m  = m0 + a_ml;
        int b  = m & 63;
        int tl = m >> 6;
        int idx = targets[b * U_ + t0 + tl];
        a_ptr = A + (size_t)idx * E_ + a_kq;
    } else {
        a_k  = tid >> 5;                // 0..7
        a_ml = (tid & 31) * 4;          // row group of 4 (consecutive b)
        int m  = m0 + a_ml;
        int b  = m & 63;
        int tl = m >> 6;
        a_ptr = A + (size_t)tl * (D_ * 64) + (size_t)a_k * 64 + b;
    }
    // B loader: k = tid>>5 (0..7), n4 = (tid&31)*4
    const int b_k  = tid >> 5;
    const int b_n4 = (tid & 31) * 4;

    const int tx = tid & 15;            // n tile index
    const int ty = tid >> 4;            // m tile index

    for (int k0 = 0; k0 < K; k0 += 8) {
        // stage A
        if (MODE == 0) {
            float4 av = *(const float4*)(a_ptr + k0);
            As[a_kq + 0][a_ml] = av.x;
            As[a_kq + 1][a_ml] = av.y;
            As[a_kq + 2][a_ml] = av.z;
            As[a_kq + 3][a_ml] = av.w;
        } else {
            float4 av = *(const float4*)(a_ptr + (size_t)k0 * 64);
            *(float4*)&As[a_k][a_ml] = av;
        }
        // stage B
        {
            float4 bv = *(const float4*)(Wm + (size_t)(k0 + b_k) * L4_ + n0 + b_n4);
            *(float4*)&Bs[b_k][b_n4] = bv;
        }
        __syncthreads();

#pragma unroll
        for (int k = 0; k < 8; ++k) {
            float af[8], bf[8];
            *(float4*)&af[0] = *(const float4*)&As[k][ty * 8];
            *(float4*)&af[4] = *(const float4*)&As[k][ty * 8 + 4];
            *(float4*)&bf[0] = *(const float4*)&Bs[k][tx * 8];
            *(float4*)&bf[4] = *(const float4*)&Bs[k][tx * 8 + 4];
#pragma unroll
            for (int i = 0; i < 8; ++i)
#pragma unroll
                for (int j = 0; j < 8; ++j) acc[i][j] += af[i] * bf[j];
        }
        __syncthreads();
    }

    // epilogue: C[m][n] -> xz[tl][n][b] with m = tl*64 + b
#pragma unroll
    for (int i = 0; i < 8; ++i) {
        int m  = m0 + ty * 8 + i;
        int tl = m >> 6;
        int b  = m & 63;
        float* outp = xz + (size_t)tl * (L4_ * 64) + b;
#pragma unroll
        for (int j = 0; j < 8; ++j) {
            int n = n0 + tx * 8 + j;
            outp[(size_t)n * 64] = acc[i][j] + bias[n];
        }
    }
}

// ---------------------------------------------------------------------------
// One LSTM timestep. Grid: 640 WGs (one hidden dim d each), 256 threads
// (64 batch x 4 K-splits). h buffers are transposed [d][b] for coalescing.
// Ping-pong h (read h_prev, write h_next) avoids cross-WG RAW races.
// ---------------------------------------------------------------------------
__global__ __launch_bounds__(256) void step_kernel(
    const float* __restrict__ xz,      // [TC][2560][64]
    const float* __restrict__ Uw,      // [640][2560]
    const float* __restrict__ h_prev,  // [640][64]
    float* __restrict__ h_next,        // [640][64]
    float* __restrict__ c_st,          // [640][64]
    const int* __restrict__ lens,      // [64]
    float* __restrict__ hc_out,        // [TC][640][64]
    int t_glob, int tloc)
{
    const int d  = blockIdx.x;
    const int b  = threadIdx.x & 63;
    const int ks = threadIdx.x >> 6;   // 0..3

    float p0 = 0.f, p1 = 0.f, p2 = 0.f, p3 = 0.f;
    const float* hp = h_prev + b;
    const float* up = Uw + d;          // wave-uniform addressing -> scalar loads
    const int kbeg = ks * 160;
    const int kend = kbeg + 160;
    for (int k = kbeg; k < kend; ++k) {
        float hv = hp[(size_t)k * 64];
        float u0 = up[(size_t)k * L4_];
        float u1 = up[(size_t)k * L4_ + 640];
        float u2 = up[(size_t)k * L4_ + 1280];
        float u3 = up[(size_t)k * L4_ + 1920];
        p0 += hv * u0;
        p1 += hv * u1;
        p2 += hv * u2;
        p3 += hv * u3;
    }

    __shared__ float red[16][64];      // [g*4 + ks][b]
    red[ks +  0][b] = p0;
    red[ks +  4][b] = p1;
    red[ks +  8][b] = p2;
    red[ks + 12][b] = p3;
    __syncthreads();

    if (threadIdx.x < 64) {
        const int bb = threadIdx.x;
        const float* xzp = xz + (size_t)tloc * (L4_ * 64) + bb;
        float z[4];
#pragma unroll
        for (int g = 0; g < 4; ++g) {
            float s = red[g * 4 + 0][bb] + red[g * 4 + 1][bb] +
                      red[g * 4 + 2][bb] + red[g * 4 + 3][bb];
            z[g] = s + xzp[(size_t)(d + 640 * g) * 64];
        }
        float ig = 1.f / (1.f + __expf(-z[0]));
        float fg = 1.f / (1.f + __expf(-z[1]));
        float gg = tanhf(z[2]);
        float og = 1.f / (1.f + __expf(-z[3]));

        float c_old = c_st[d * 64 + bb];
        float c_new = fg * c_old + ig * gg;
        float h_new = og * tanhf(c_new);

        bool msk = t_glob < lens[bb];
        float h_out = msk ? h_new : h_prev[d * 64 + bb];
        float c_out = msk ? c_new : c_old;

        c_st[d * 64 + bb]   = c_out;
        h_next[d * 64 + bb] = h_out;
        hc_out[(size_t)tloc * (D_ * 64) + d * 64 + bb] = h_out;
    }
}

// ---------------------------------------------------------------------------
// Transpose chunk h1c [tl][d][b] -> out [b][t0+tl][d]
// Grid: (TC, 10); 256 threads; 64x64 (d,b) tiles through LDS.
// ---------------------------------------------------------------------------
__global__ __launch_bounds__(256) void transpose_kernel(
    const float* __restrict__ h1c, float* __restrict__ out, int t0)
{
    const int tl   = blockIdx.x;
    const int dblk = blockIdx.y;
    __shared__ float tile[64][65];

    const int r  = threadIdx.x >> 2;   // 0..63
    const int cq = threadIdx.x & 3;    // 0..3

    // load: h1c[tl][dblk*64 + r][cq*16 .. +16]
    const float* src = h1c + (size_t)tl * (D_ * 64) + (size_t)(dblk * 64 + r) * 64 + cq * 16;
#pragma unroll
    for (int j = 0; j < 4; ++j) {
        float4 v = *(const float4*)(src + j * 4);
        tile[r][cq * 16 + j * 4 + 0] = v.x;
        tile[r][cq * 16 + j * 4 + 1] = v.y;
        tile[r][cq * 16 + j * 4 + 2] = v.z;
        tile[r][cq * 16 + j * 4 + 3] = v.w;
    }
    __syncthreads();

    // store: out[b=r][t0+tl][dblk*64 + cq*16 .. +16] = tile[d][b]
    float* dst = out + (size_t)r * (U_ * D_) + (size_t)(t0 + tl) * D_ + dblk * 64 + cq * 16;
#pragma unroll
    for (int j = 0; j < 4; ++j) {
        float4 w;
        w.x = tile[cq * 16 + j * 4 + 0][r];
        w.y = tile[cq * 16 + j * 4 + 1][r];
        w.z = tile[cq * 16 + j * 4 + 2][r];
        w.w = tile[cq * 16 + j * 4 + 3][r];
        *(float4*)(dst + j * 4) = w;
    }
}

// ---------------------------------------------------------------------------
extern "C" void kernel_launch(void* const* d_in, const int* in_sizes, int n_in,
                              void* d_out, int out_size, void* d_ws, size_t ws_size,
                              hipStream_t stream)
{
    const int*   targets = (const int*)d_in[0];
    const int*   lens    = (const int*)d_in[1];
    const float* embed   = (const float*)d_in[2];
    const float* W0      = (const float*)d_in[3];
    const float* U0      = (const float*)d_in[4];
    const float* b0      = (const float*)d_in[5];
    const float* W1      = (const float*)d_in[6];
    const float* U1      = (const float*)d_in[7];
    const float* b1      = (const float*)d_in[8];
    float* out = (float*)d_out;
    float* ws  = (float*)d_ws;

    // workspace layout (floats)
    float* xz  = ws;                                   // TC*2560*64 = 10,485,760
    float* h0c = xz  + (size_t)TC * L4_ * 64;          // TC*640*64  =  2,621,440
    float* h1c = h0c + (size_t)TC * D_ * 64;           // TC*640*64
    float* st  = h1c + (size_t)TC * D_ * 64;           // 6 * 40,960 state buffers
    float* h0a = st;
    float* h0b = st + 40960;
    float* c0  = st + 2 * 40960;
    float* h1a = st + 3 * 40960;
    float* h1b = st + 4 * 40960;
    float* c1  = st + 5 * 40960;

    // zero-init states (ws is poisoned 0xAA before every call)
    hipMemsetAsync(st, 0, (size_t)6 * 40960 * sizeof(float), stream);

    const dim3 gemm_grid(TC * 64 / 128, L4_ / 128);    // (32, 20)
    const dim3 blk(256);

    for (int ch = 0; ch < NCH; ++ch) {
        const int t0 = ch * TC;

        // layer 0 input transform: xz = embed[targets] @ W0 + b0
        gemm_kernel<0><<<gemm_grid, blk, 0, stream>>>(embed, targets, W0, b0, xz, E_, t0);

        for (int tl = 0; tl < TC; ++tl) {
            const int t = t0 + tl;
            float* hprev = (t & 1) ? h0b : h0a;
            float* hnext = (t & 1) ? h0a : h0b;
            step_kernel<<<dim3(D_), blk, 0, stream>>>(xz, U0, hprev, hnext, c0, lens, h0c, t, tl);
        }

        // layer 1 input transform: xz = h0c @ W1 + b1
        gemm_kernel<1><<<gemm_grid, blk, 0, stream>>>(h0c, targets, W1, b1, xz, D_, t0);

        for (int tl = 0; tl < TC; ++tl) {
            const int t = t0 + tl;
            float* hprev = (t & 1) ? h1b : h1a;
            float* hnext = (t & 1) ? h1a : h1b;
            step_kernel<<<dim3(D_), blk, 0, stream>>>(xz, U1, hprev, hnext, c1, lens, h1c, t, tl);
        }

        // emit chunk to output
        transpose_kernel<<<dim3(TC, 10), blk, 0, stream>>>(h1c, out, t0);
    }
}